// Round 10
// baseline (392428.345 us; speedup 1.0000x reference)
//
#include <hip/hip_runtime.h>
#include <hip/hip_cooperative_groups.h>

namespace cg = cooperative_groups;

// ---------------------------------------------------------------------------
// ROUND-10: round-9 fp32 oracle + FLOAT32 OUTPUT (the actual bug all along).
// Forensics: reported absmax values across rounds are explained to 7 digits
// by: d_out is float32 (reference output dtype is fp32; harness maps
// "bfloat16 -> __hip_bfloat16*, else float*"), with the harness bf16-rounding
// the actual before comparing. Round 1: |bf16(1e9)-ref[0]| = 998244352.038 ✓.
// Rounds 6/7: bf16-round(0x4EEE4EEE) = 1996488704 ✓. Rounds 2-5/8/9: my bf16
// writes packed pairwise into float elements -> act[j] ~ mine[2j+1] compared
// vs ref[j] -> decorrelated absmax 0.1077, bit-identical across all correct
// implementations ✓. So: computation correct since round 2; output dtype
// wrong since round 2. This round changes ONLY the output type/writes.
// Sentinels (float): <5e8 = ws MB*1e6 | 2e12 = coop launch failed.
// ---------------------------------------------------------------------------

#define HD 512
#define SEQ 512
#define NTHREADS 512

constexpr size_t HSZ  = (size_t)256 * HD * 4;     // one fp32 h-plane (512 KiB)
constexpr size_t H0N  = 0;                        // layer-0 final h
constexpr size_t HP0  = HSZ;                      // L0 recurrent ping-pong [2]
constexpr size_t R01  = HP0 + 2 * HSZ;            // L0 -> L1 ring [3]
constexpr size_t R12  = R01 + 3 * HSZ;            // L1 out ring   [3]
constexpr size_t H2P  = R12 + 3 * HSZ;            // L2 ping-pong  [2]
constexpr size_t WS_NEED = H2P + 2 * HSZ;         // 5.5 MiB

// 4-gate fused dot: pre[g] += sum_k w_g[k] * h[k]
__device__ inline void dot4(const float* __restrict__ w0, const float* __restrict__ w1,
                            const float* __restrict__ w2, const float* __restrict__ w3,
                            const float* __restrict__ h, float* __restrict__ pre) {
  float a0 = 0.f, a1 = 0.f, a2 = 0.f, a3 = 0.f;
#pragma unroll 4
  for (int k = 0; k < HD; k += 4) {
    const float4 hv = *(const float4*)(h + k);
    const float4 v0 = *(const float4*)(w0 + k);
    const float4 v1 = *(const float4*)(w1 + k);
    const float4 v2 = *(const float4*)(w2 + k);
    const float4 v3 = *(const float4*)(w3 + k);
    a0 += v0.x * hv.x + v0.y * hv.y + v0.z * hv.z + v0.w * hv.w;
    a1 += v1.x * hv.x + v1.y * hv.y + v1.z * hv.z + v1.w * hv.w;
    a2 += v2.x * hv.x + v2.y * hv.y + v2.z * hv.z + v2.w * hv.w;
    a3 += v3.x * hv.x + v3.y * hv.y + v3.z * hv.z + v3.w * hv.w;
  }
  pre[0] += a0; pre[1] += a1; pre[2] += a2; pre[3] += a3;
}

// PyTorch/JAX LSTM cell: i,f,g,o gate order
__device__ inline float cellup(const float* pre, float& c) {
  const float gi = 1.f / (1.f + expf(-pre[0]));
  const float gf = 1.f / (1.f + expf(-pre[1]));
  const float gg = tanhf(pre[2]);
  const float go = 1.f / (1.f + expf(-pre[3]));
  c = gf * c + gi * gg;
  return go * tanhf(c);
}

__global__ __launch_bounds__(NTHREADS, 1) void lstm_oracle(
    const float* __restrict__ x,
    const float* __restrict__ wih0, const float* __restrict__ whh0,
    const float* __restrict__ bih0, const float* __restrict__ bhh0,
    const float* __restrict__ wih1, const float* __restrict__ whh1,
    const float* __restrict__ bih1, const float* __restrict__ bhh1,
    const float* __restrict__ wih2, const float* __restrict__ whh2,
    const float* __restrict__ bih2, const float* __restrict__ bhh2,
    const float* __restrict__ wfc, const float* __restrict__ bfc,
    float* __restrict__ out, char* __restrict__ ws) {
  cg::grid_group grid = cg::this_grid();
  const int bid = blockIdx.x, tid = threadIdx.x;
  const int bt = bid >> 4, ct = bid & 15;
  const int b   = bt * 16 + (tid >> 5);     // global batch row owned
  const int col = ct * 32 + (tid & 31);     // hidden column owned
  const size_t bb = (size_t)b * HD;         // h-row base
  constexpr size_t HP = (size_t)256 * HD;   // h-plane stride in floats

  float* h0N = (float*)(ws + H0N);
  float* hp0 = (float*)(ws + HP0);
  float* r01 = (float*)(ws + R01);
  float* r12 = (float*)(ws + R12);
  float* h2p = (float*)(ws + H2P);

  // hoisted per-cell constants: biases, layer-0 input column, weight rows
  float bs[3][4], w0c[4];
  const float* whhp[3][4];
  const float* wihp[2][4];
#pragma unroll
  for (int g = 0; g < 4; ++g) {
    const int j = g * HD + col;
    bs[0][g] = bih0[j] + bhh0[j];
    bs[1][g] = bih1[j] + bhh1[j];
    bs[2][g] = bih2[j] + bhh2[j];
    w0c[g]   = wih0[j];                       // Wih0 is (2048, 1)
    whhp[0][g] = whh0 + (size_t)j * HD;
    whhp[1][g] = whh1 + (size_t)j * HD;
    whhp[2][g] = whh2 + (size_t)j * HD;
    wihp[0][g] = wih1 + (size_t)j * HD;
    wihp[1][g] = wih2 + (size_t)j * HD;
  }

  // ---------------- pass 1: layer 0 only -> (hN, cN) ------------------------
  float c0 = 0.f, c0sav = 0.f;
  for (int t = 0; t < SEQ; ++t) {
    const float xv = x[(size_t)b * SEQ + t];
    float pre[4];
#pragma unroll
    for (int g = 0; g < 4; ++g) pre[g] = bs[0][g] + xv * w0c[g];
    if (t) dot4(whhp[0][0], whhp[0][1], whhp[0][2], whhp[0][3],
                hp0 + (size_t)((t - 1) & 1) * HP + bb, pre);
    const float h = cellup(pre, c0);
    hp0[(size_t)(t & 1) * HP + bb + col] = h;
    if (t == SEQ - 1) { c0sav = c0; h0N[bb + col] = h; }
    grid.sync();
  }

  // ---------------- pass 2: L0 recompute || L1 (lag 1) || L2 (lag 2) --------
  float c0b = 0.f, c1 = 0.f, c2 = 0.f;
  for (int i = 0; i < SEQ + 2; ++i) {
    if (i < SEQ) {                            // L0 step t0 = i (bit-identical rerun)
      const int t0 = i;
      const float xv = x[(size_t)b * SEQ + t0];
      float pre[4];
#pragma unroll
      for (int g = 0; g < 4; ++g) pre[g] = bs[0][g] + xv * w0c[g];
      if (t0) dot4(whhp[0][0], whhp[0][1], whhp[0][2], whhp[0][3],
                   hp0 + (size_t)((t0 - 1) & 1) * HP + bb, pre);
      const float h = cellup(pre, c0b);
      hp0[(size_t)(t0 & 1) * HP + bb + col] = h;
      r01[(size_t)(t0 % 3) * HP + bb + col] = h;
    }
    if (i >= 1 && i <= SEQ) {                 // L1 step t1 = i-1
      const int t1 = i - 1;
      float pre[4];
#pragma unroll
      for (int g = 0; g < 4; ++g) pre[g] = bs[1][g];
      const float* hrec = (t1 ? r12 + (size_t)((t1 - 1) % 3) * HP : h0N) + bb;
      dot4(whhp[1][0], whhp[1][1], whhp[1][2], whhp[1][3], hrec, pre);
      dot4(wihp[0][0], wihp[0][1], wihp[0][2], wihp[0][3],
           r01 + (size_t)(t1 % 3) * HP + bb, pre);
      if (t1 == 0) c1 = c0sav;
      const float h = cellup(pre, c1);
      r12[(size_t)(t1 % 3) * HP + bb + col] = h;
    }
    if (i >= 2) {                             // L2 step t2 = i-2
      const int t2 = i - 2;
      float pre[4];
#pragma unroll
      for (int g = 0; g < 4; ++g) pre[g] = bs[2][g];
      const float* hrec = (t2 ? h2p + (size_t)((t2 - 1) & 1) * HP : h0N) + bb;
      dot4(whhp[2][0], whhp[2][1], whhp[2][2], whhp[2][3], hrec, pre);
      dot4(wihp[1][0], wihp[1][1], wihp[1][2], wihp[1][3],
           r12 + (size_t)(t2 % 3) * HP + bb, pre);
      if (t2 == 0) c2 = c0sav;
      const float h = cellup(pre, c2);
      h2p[(size_t)(t2 & 1) * HP + bb + col] = h;
    }
    grid.sync();
  }

  // ---------------- FC: out[b,:] = h2(511)[b,:] @ Wfc^T + bfc (FLOAT32) -----
  {
    const float* h2 = h2p + (size_t)((SEQ - 1) & 1) * HP + (size_t)bid * HD;
    if (tid < 96) {
      const float* wr = wfc + (size_t)tid * HD;
      float a = bfc[tid];
#pragma unroll 4
      for (int k = 0; k < HD; k += 4) {
        const float4 hv = *(const float4*)(h2 + k);
        const float4 wv = *(const float4*)(wr + k);
        a += wv.x * hv.x + wv.y * hv.y + wv.z * hv.z + wv.w * hv.w;
      }
      out[(size_t)bid * 96 + tid] = a;     // float32 output
    }
  }
}

__global__ void ws_info_kernel(float* out, float v) { out[0] = v; }

extern "C" void kernel_launch(void* const* d_in, const int* in_sizes, int n_in,
                              void* d_out, int out_size, void* d_ws, size_t ws_size,
                              hipStream_t stream) {
  const float* x    = (const float*)d_in[0];
  const float* wih0 = (const float*)d_in[1];
  const float* whh0 = (const float*)d_in[2];
  const float* bih0 = (const float*)d_in[3];
  const float* bhh0 = (const float*)d_in[4];
  const float* wih1 = (const float*)d_in[5];
  const float* whh1 = (const float*)d_in[6];
  const float* bih1 = (const float*)d_in[7];
  const float* bhh1 = (const float*)d_in[8];
  const float* wih2 = (const float*)d_in[9];
  const float* whh2 = (const float*)d_in[10];
  const float* bih2 = (const float*)d_in[11];
  const float* bhh2 = (const float*)d_in[12];
  const float* wfc  = (const float*)d_in[13];
  const float* bfc  = (const float*)d_in[14];
  float* out = (float*)d_out;
  char* ws = (char*)d_ws;

  if (ws_size < WS_NEED) {
    hipLaunchKernelGGL(ws_info_kernel, dim3(1), dim3(1), 0, stream, out,
                       (float)(ws_size >> 20) * 1.0e6f);
    return;
  }

  void* args[] = {(void*)&x,
                  (void*)&wih0, (void*)&whh0, (void*)&bih0, (void*)&bhh0,
                  (void*)&wih1, (void*)&whh1, (void*)&bih1, (void*)&bhh1,
                  (void*)&wih2, (void*)&whh2, (void*)&bih2, (void*)&bhh2,
                  (void*)&wfc, (void*)&bfc, (void*)&out, (void*)&ws};
  hipError_t e = hipLaunchCooperativeKernel((const void*)lstm_oracle,
                                            dim3(256), dim3(NTHREADS),
                                            args, 0, stream);
  if (e != hipSuccess) {
    hipLaunchKernelGGL(ws_info_kernel, dim3(1), dim3(1), 0, stream, out, 2.0e12f);
  }
}

// Round 11
// 17982.755 us; speedup vs baseline: 21.8225x; 21.8225x over previous
//
#include <hip/hip_runtime.h>
#include <stdint.h>

// ---------------------------------------------------------------------------
// 3-layer LSTM (B=256,S=512,H=512) + FC(96) -> FLOAT32 out. ROUND-11.
// Fast path (rounds 2-5 architecture, computation verified ≡ fp32 oracle
// through bf16 rounding; round-10 proved output dtype was the only bug).
//  * 8 batch-groups x 32 blocks; block (grp,cg) owns h-cols [cg*16,cg*16+16)
//    for its 32-batch tile, all 4 gates => c stays in registers.
//  * fp16 weights LDS-resident (132KB), staged from pre-converted ws image.
//  * mfma_f32_16x16x32_f16 (layout H1, HW-verified rounds 4/5).
//  * L0 full pass -> seq0; then L1/L2 interleaved in 64-step chunks
//    (65-slot ring, 2-slot h2 double buffer). 1536 serial steps.
//  * per-group 32-block flag barrier (bit-identical to grid.sync, round 2≡3).
// Sentinels (float out[0]): <5e8 ws-MB*1e6 | 2e12 launch-fail | 3e9 spin-cap.
// ---------------------------------------------------------------------------

#define NGRP 8
#define BPG 32
#define HD 512
#define SEQ 512
#define TCHUNK 64
#define RSLOTS (TCHUNK + 1)
#define TILE_H (BPG * HD)          // halves per group-tile [32][512]
#define KPAD 1032                  // halves; row stride 2064B (bank spread)
#define NTHREADS 512

typedef _Float16 f16x8 __attribute__((ext_vector_type(8)));
typedef float f32x4 __attribute__((ext_vector_type(4)));

constexpr size_t W0_OFF   = (size_t)1 << 16;
constexpr size_t W0_SZ    = (size_t)32 * 64 * 512 * 2;           // 2MB
constexpr size_t W1_OFF   = W0_OFF + W0_SZ;
constexpr size_t W1_SZ    = (size_t)32 * 64 * 1024 * 2;          // 4MB
constexpr size_t W2_OFF   = W1_OFF + W1_SZ;
constexpr size_t H2_OFF   = W2_OFF + W1_SZ;
constexpr size_t H2_SZ    = (size_t)2 * NGRP * TILE_H * 2;       // 512KB
constexpr size_t RING_OFF = H2_OFF + H2_SZ;
constexpr size_t RING_SZ  = (size_t)RSLOTS * NGRP * TILE_H * 2;  // 16.6MB
constexpr size_t SEQ0_OFF = RING_OFF + RING_SZ;
constexpr size_t SEQ0_SZ  = (size_t)NGRP * SEQ * TILE_H * 2;     // 128MB
constexpr size_t WS_NEED  = SEQ0_OFF + SEQ0_SZ;                  // ~155MB

__device__ inline float sigm(float v) { return 1.f / (1.f + __expf(-v)); }
__device__ inline float tanhf_(float v) {
  float av = fabsf(v);
  float e = __expf(-2.f * av);
  float t = (1.f - e) / (1.f + e);
  return copysignf(t, v);
}

// ---- weight pre-conversion: fp32 [g*512+cg*16+nl][k] -> fp16 image laid out
// so block cg's 64 rows x K are contiguous: dst[(cg*64 + g*16+nl)*K + k],
// k<512 = Whh, k>=512 = Wih (layers 1,2). [verified bit-exact, round 5]
template <int K>
__global__ void convw(const float* __restrict__ whh, const float* __restrict__ wih,
                      _Float16* __restrict__ dst) {
  const int i = blockIdx.x * blockDim.x + threadIdx.x;   // one per 4 halves
  constexpr int TOT = 32 * 64 * K / 4;
  if (i >= TOT) return;
  const int kq = i % (K / 4);
  const int rr = i / (K / 4);
  const int cg = rr >> 6, r = rr & 63;
  const int grow = (r >> 4) * 512 + cg * 16 + (r & 15);
  const int k = kq * 4;
  const float* src = (k < 512) ? (whh + (size_t)grow * 512 + k)
                               : (wih + (size_t)grow * 512 + (k - 512));
  float4 v = *(const float4*)src;
  _Float16 o[4] = {(_Float16)v.x, (_Float16)v.y, (_Float16)v.z, (_Float16)v.w};
  *(uint64_t*)(dst + (size_t)i * 4) = *(const uint64_t*)o;
}

// ---- copy this block's 64 x K fp16 weights from ws image into LDS ----------
template <int K>
__device__ inline void stage_w(const _Float16* __restrict__ src,
                               _Float16* __restrict__ wlds, int tid) {
  constexpr int C = 64 * K / 8;
#pragma unroll 4
  for (int ci = tid; ci < C; ci += NTHREADS) {
    const int r = ci / (K / 8);
    const int kc = (ci % (K / 8)) * 8;
    *(f16x8*)(wlds + (size_t)r * KPAD + kc) = *(const f16x8*)(src + (size_t)r * K + kc);
  }
}

// ---- one wave's share of the step GEMM [verified H1 mapping, rounds 4/5] ---
template <int NS>
__device__ inline void do_gemm(const _Float16* __restrict__ bbase,
                               const _Float16* __restrict__ wlds,
                               int aKoff, int bKoff, int lane, int gt,
                               f32x4& acc0, f32x4& acc1) {
  const int bcol = lane & 15;
  const int krow = (lane >> 4) * 8;
  const _Float16* arow  = wlds + (size_t)(gt * 16 + (lane & 15)) * KPAD + aKoff + krow;
  const _Float16* brow0 = bbase + (size_t)bcol * HD + bKoff + krow;
  const _Float16* brow1 = bbase + (size_t)(bcol + 16) * HD + bKoff + krow;
  constexpr int CH = (NS > 8) ? 8 : NS;
#pragma unroll
  for (int base = 0; base < NS; base += CH) {
    f16x8 br0[CH], br1[CH];
#pragma unroll
    for (int s = 0; s < CH; ++s) {
      br0[s] = *(const f16x8*)(brow0 + (base + s) * 32);
      br1[s] = *(const f16x8*)(brow1 + (base + s) * 32);
    }
#pragma unroll
    for (int s = 0; s < CH; ++s) {
      f16x8 a = *(const f16x8*)(arow + (base + s) * 32);
      acc0 = __builtin_amdgcn_mfma_f32_16x16x32_f16(a, br0[s], acc0, 0, 0, 0);
      acc1 = __builtin_amdgcn_mfma_f32_16x16x32_f16(a, br1[s], acc1, 0, 0, 0);
    }
  }
}

// ---- per-group flag barrier (32 blocks) [verified ≡ grid.sync, rounds 2/3] -
__device__ inline void group_barrier(unsigned* slots, int cg, unsigned target,
                                     int lane, int wave, bool& dead) {
  __syncthreads();
  if (wave == 0) {
    if (lane == 0) {
      __builtin_amdgcn_fence(__ATOMIC_RELEASE, "agent");
      __hip_atomic_store(&slots[cg], target, __ATOMIC_RELAXED, __HIP_MEMORY_SCOPE_AGENT);
    }
    if (!dead) {
      unsigned* myslot = &slots[lane & 31];
      int spins = 0;
      while (true) {
        unsigned v = __hip_atomic_load(myslot, __ATOMIC_RELAXED, __HIP_MEMORY_SCOPE_AGENT);
        if (__all((int)(v >= target))) break;
        __builtin_amdgcn_s_sleep(1);
        if (++spins > (1 << 22)) { dead = true; break; }
      }
    }
    if (lane == 0) __builtin_amdgcn_fence(__ATOMIC_ACQUIRE, "agent");
  }
  __syncthreads();
}

__global__ __launch_bounds__(NTHREADS, 2) void lstm3_kernel(
    const float* __restrict__ x,
    const float* __restrict__ wih0,
    const float* __restrict__ bih0, const float* __restrict__ bhh0,
    const float* __restrict__ bih1, const float* __restrict__ bhh1,
    const float* __restrict__ bih2, const float* __restrict__ bhh2,
    const float* __restrict__ wfc, const float* __restrict__ bfc,
    float* __restrict__ out, char* __restrict__ ws) {
  __shared__ __align__(16) char smem[149504];
  _Float16* wlds = (_Float16*)smem;                 // [64][KPAD] fp16
  float* biasLds = (float*)(smem + 132096);         // [64]
  float* w0Lds   = (float*)(smem + 132352);         // [64] layer-0 input col
  float* gmat    = (float*)(smem + 132608);         // [8][16][33] f32

  const int bid = blockIdx.x;
  const int grp = bid & 7;
  const int cg  = bid >> 3;
  const int tid = threadIdx.x;
  const int lane = tid & 63;
  const int wave = tid >> 6;
  const int gt = wave & 3;       // gate tile 0..3 (i,f,g,o)
  const int kh = wave >> 2;      // K half 0/1
  const int nbase = cg * 16;
  const int ab = tid >> 4;       // epilogue cell: local batch 0..31
  const int an = tid & 15;       // epilogue cell: local col 0..15

  unsigned* bar = (unsigned*)ws + grp * 64;
  const _Float16* wcv0 = (const _Float16*)(ws + W0_OFF) + (size_t)cg * 64 * 512;
  const _Float16* wcv1 = (const _Float16*)(ws + W1_OFF) + (size_t)cg * 64 * 1024;
  const _Float16* wcv2 = (const _Float16*)(ws + W2_OFF) + (size_t)cg * 64 * 1024;
  _Float16* h2b  = (_Float16*)(ws + H2_OFF);
  _Float16* ring = (_Float16*)(ws + RING_OFF);
  _Float16* seq0 = (_Float16*)(ws + SEQ0_OFF);

  unsigned barIdx = 0;
  bool dead = false;

  auto seqTile  = [&](int t) { return seq0 + ((size_t)(grp * SEQ + t)) * TILE_H; };
  auto ringTile = [&](int t) { return ring + ((size_t)(t % RSLOTS) * NGRP + grp) * TILE_H; };
  auto h2Tile   = [&](int s) { return h2b + ((size_t)s * NGRP + grp) * TILE_H; };

  auto step = [&](const _Float16* recB, const _Float16* inB, float xv, float& cst,
                  _Float16* houtTile, bool skip) {
    f32x4 acc0 = {0.f, 0.f, 0.f, 0.f};
    f32x4 acc1 = {0.f, 0.f, 0.f, 0.f};
    if (!skip) {
      if (inB == nullptr) {
        do_gemm<8>(recB, wlds, kh * 256, kh * 256, lane, gt, acc0, acc1);
      } else {
        const _Float16* bb = kh ? inB : recB;
        do_gemm<16>(bb, wlds, kh * 512, 0, lane, gt, acc0, acc1);
      }
    }
    {
      const int r0 = (lane >> 4) * 4, cb = lane & 15;
      const int rowbase = (kh * 4 + gt) * 16;
#pragma unroll
      for (int r = 0; r < 4; ++r) {
        gmat[(rowbase + r0 + r) * 33 + cb]      = acc0[r];
        gmat[(rowbase + r0 + r) * 33 + 16 + cb] = acc1[r];
      }
    }
    __syncthreads();
    float pre[4];
#pragma unroll
    for (int g = 0; g < 4; ++g) {
      float s = gmat[(g * 16 + an) * 33 + ab] + gmat[((4 + g) * 16 + an) * 33 + ab];
      pre[g] = s + biasLds[g * 16 + an] + xv * w0Lds[g * 16 + an];
    }
    const float gi = sigm(pre[0]);
    const float gf = sigm(pre[1]);
    const float gg = tanhf_(pre[2]);
    const float go = sigm(pre[3]);
    cst = gf * cst + gi * gg;
    const float h = go * tanhf_(cst);
    houtTile[(size_t)ab * HD + nbase + an] = (_Float16)h;
    group_barrier(bar, cg, ++barIdx, lane, wave, dead);
  };

  // ---------------- phase A: layer 0 (K=512, input is scalar x) -------------
  stage_w<512>(wcv0, wlds, tid);
  if (tid < 64) {
    const int grow2 = (tid >> 4) * 512 + nbase + (tid & 15);
    biasLds[tid] = bih0[grow2] + bhh0[grow2];
    w0Lds[tid] = wih0[grow2];
  }
  __syncthreads();

  float c0 = 0.f;
  for (int t = 0; t < SEQ; ++t) {
    const _Float16* recB = t ? seqTile(t - 1) : seq0;
    const float xv = x[(size_t)(grp * 32 + ab) * SEQ + t];
    step(recB, nullptr, xv, c0, seqTile(t), t == 0);
  }
  const float c0sav = c0;
  const _Float16* h0tile = seqTile(SEQ - 1);

  // ---------------- phase B: layers 1+2 interleaved in chunks ---------------
  float c1 = c0sav, c2 = c0sav;
  for (int ch = 0; ch < SEQ / TCHUNK; ++ch) {
    // L1 sub-phase
    __syncthreads();             // wlds readers done before restage
    stage_w<1024>(wcv1, wlds, tid);
    if (tid < 64) {
      const int grow2 = (tid >> 4) * 512 + nbase + (tid & 15);
      biasLds[tid] = bih1[grow2] + bhh1[grow2];
      w0Lds[tid] = 0.f;
    }
    __syncthreads();
    for (int tt = 0; tt < TCHUNK; ++tt) {
      const int t = ch * TCHUNK + tt;
      const _Float16* recB = t ? ringTile(t - 1) : h0tile;
      step(recB, seqTile(t), 0.f, c1, ringTile(t), false);
    }
    // L2 sub-phase
    __syncthreads();
    stage_w<1024>(wcv2, wlds, tid);
    if (tid < 64) {
      const int grow2 = (tid >> 4) * 512 + nbase + (tid & 15);
      biasLds[tid] = bih2[grow2] + bhh2[grow2];
      w0Lds[tid] = 0.f;
    }
    __syncthreads();
    for (int tt = 0; tt < TCHUNK; ++tt) {
      const int t = ch * TCHUNK + tt;
      const _Float16* recB = t ? h2Tile((t - 1) & 1) : h0tile;
      step(recB, ringTile(t), 0.f, c2, h2Tile(t & 1), false);
    }
  }

  // ---------------- final FC: out[b,:] = h2[b,:] @ Wfc^T + bfc (FLOAT32) ----
  {
    const _Float16* h2 = h2Tile((SEQ - 1) & 1) + (size_t)cg * HD;  // batch row cg
    if (tid < 384) {
      const int pc = tid >> 2, kq = tid & 3;
      const float* wrow = wfc + (size_t)pc * HD + kq * 128;
      const _Float16* hh = h2 + kq * 128;
      float a = 0.f;
#pragma unroll 8
      for (int k2 = 0; k2 < 128; ++k2) a += (float)hh[k2] * wrow[k2];
      gmat[pc * 4 + kq] = a;
    }
    __syncthreads();
    if (tid < 96) {
      const float a = gmat[tid * 4] + gmat[tid * 4 + 1] + gmat[tid * 4 + 2] +
                      gmat[tid * 4 + 3] + bfc[tid];
      out[(size_t)(grp * 32 + cg) * 96 + tid] = a;
    }
    if (dead && tid == 0)
      out[(size_t)(grp * 32 + cg) * 96] = 3.0e9f;   // spin-cap diagnostic
  }
}

__global__ void ws_info_kernel(float* out, float v) { out[0] = v; }

extern "C" void kernel_launch(void* const* d_in, const int* in_sizes, int n_in,
                              void* d_out, int out_size, void* d_ws, size_t ws_size,
                              hipStream_t stream) {
  const float* x    = (const float*)d_in[0];
  const float* wih0 = (const float*)d_in[1];
  const float* whh0 = (const float*)d_in[2];
  const float* bih0 = (const float*)d_in[3];
  const float* bhh0 = (const float*)d_in[4];
  const float* wih1 = (const float*)d_in[5];
  const float* whh1 = (const float*)d_in[6];
  const float* bih1 = (const float*)d_in[7];
  const float* bhh1 = (const float*)d_in[8];
  const float* wih2 = (const float*)d_in[9];
  const float* whh2 = (const float*)d_in[10];
  const float* bih2 = (const float*)d_in[11];
  const float* bhh2 = (const float*)d_in[12];
  const float* wfc  = (const float*)d_in[13];
  const float* bfc  = (const float*)d_in[14];
  float* out = (float*)d_out;
  char* ws = (char*)d_ws;

  if (ws_size < WS_NEED) {
    hipLaunchKernelGGL(ws_info_kernel, dim3(1), dim3(1), 0, stream, out,
                       (float)(ws_size >> 20) * 1.0e6f);
    return;
  }

  hipMemsetAsync(ws, 0, 4096, stream);   // barrier flags (every replay)

  _Float16* w0d = (_Float16*)(ws + W0_OFF);
  _Float16* w1d = (_Float16*)(ws + W1_OFF);
  _Float16* w2d = (_Float16*)(ws + W2_OFF);
  hipLaunchKernelGGL((convw<512>),  dim3(32 * 64 * 512 / 4 / 256),  dim3(256), 0, stream,
                     whh0, whh0, w0d);   // K=512: wih arg never accessed
  hipLaunchKernelGGL((convw<1024>), dim3(32 * 64 * 1024 / 4 / 256), dim3(256), 0, stream,
                     whh1, wih1, w1d);
  hipLaunchKernelGGL((convw<1024>), dim3(32 * 64 * 1024 / 4 / 256), dim3(256), 0, stream,
                     whh2, wih2, w2d);

  void* args[] = {(void*)&x, (void*)&wih0, (void*)&bih0, (void*)&bhh0,
                  (void*)&bih1, (void*)&bhh1, (void*)&bih2, (void*)&bhh2,
                  (void*)&wfc, (void*)&bfc, (void*)&out, (void*)&ws};
  hipError_t e = hipLaunchCooperativeKernel((const void*)lstm3_kernel,
                                            dim3(NGRP * BPG), dim3(NTHREADS),
                                            args, 0, stream);
  if (e != hipSuccess) {
    hipLaunchKernelGGL(ws_info_kernel, dim3(1), dim3(1), 0, stream, out, 2.0e12f);
  }
}

// Round 12
// 15993.674 us; speedup vs baseline: 24.5365x; 1.1244x over previous
//
#include <hip/hip_runtime.h>
#include <stdint.h>

// ---------------------------------------------------------------------------
// 3-layer LSTM (B=256,S=512,H=512) + FC(96) -> FLOAT32 out. ROUND-12.
// Base: round-11 (PASSED, 17983us). Two optimizations, numerics unchanged:
//  1) Wave remap (gp,nt,kh): waves sharing a B-slice differ only in A rows
//     -> B loaded once per 2 row-tiles. B traffic 256->128 KB/block/step.
//  2) L2-warming prefetch: L0-tail prefetches W1 + first-chunk seq0; L1 steps
//     prefetch W2 slice; L2 steps prefetch next chunk's seq0 + W1 slice.
//     Touch loads sunk via asm volatile, overlapped ~64 steps ahead.
// Sentinels (float out[0]): <5e8 ws-MB*1e6 | 2e12 launch-fail | 3e9 spin-cap.
// ---------------------------------------------------------------------------

#define NGRP 8
#define BPG 32
#define HD 512
#define SEQ 512
#define TCHUNK 64
#define RSLOTS (TCHUNK + 1)
#define TILE_H (BPG * HD)          // halves per group-tile [32][512]
#define KPAD 1032                  // halves; row stride 2064B (bank spread)
#define NTHREADS 512

typedef _Float16 f16x8 __attribute__((ext_vector_type(8)));
typedef float f32x4 __attribute__((ext_vector_type(4)));

constexpr size_t W0_OFF   = (size_t)1 << 16;
constexpr size_t W0_SZ    = (size_t)32 * 64 * 512 * 2;           // 2MB
constexpr size_t W1_OFF   = W0_OFF + W0_SZ;
constexpr size_t W1_SZ    = (size_t)32 * 64 * 1024 * 2;          // 4MB
constexpr size_t W2_OFF   = W1_OFF + W1_SZ;
constexpr size_t H2_OFF   = W2_OFF + W1_SZ;
constexpr size_t H2_SZ    = (size_t)2 * NGRP * TILE_H * 2;       // 512KB
constexpr size_t RING_OFF = H2_OFF + H2_SZ;
constexpr size_t RING_SZ  = (size_t)RSLOTS * NGRP * TILE_H * 2;  // 16.6MB
constexpr size_t SEQ0_OFF = RING_OFF + RING_SZ;
constexpr size_t SEQ0_SZ  = (size_t)NGRP * SEQ * TILE_H * 2;     // 128MB
constexpr size_t WS_NEED  = SEQ0_OFF + SEQ0_SZ;                  // ~155MB

__device__ inline float sigm(float v) { return 1.f / (1.f + __expf(-v)); }
__device__ inline float tanhf_(float v) {
  float av = fabsf(v);
  float e = __expf(-2.f * av);
  float t = (1.f - e) / (1.f + e);
  return copysignf(t, v);
}

// ---- weight pre-conversion (verified bit-exact, round 5) -------------------
template <int K>
__global__ void convw(const float* __restrict__ whh, const float* __restrict__ wih,
                      _Float16* __restrict__ dst) {
  const int i = blockIdx.x * blockDim.x + threadIdx.x;
  constexpr int TOT = 32 * 64 * K / 4;
  if (i >= TOT) return;
  const int kq = i % (K / 4);
  const int rr = i / (K / 4);
  const int cg = rr >> 6, r = rr & 63;
  const int grow = (r >> 4) * 512 + cg * 16 + (r & 15);
  const int k = kq * 4;
  const float* src = (k < 512) ? (whh + (size_t)grow * 512 + k)
                               : (wih + (size_t)grow * 512 + (k - 512));
  float4 v = *(const float4*)src;
  _Float16 o[4] = {(_Float16)v.x, (_Float16)v.y, (_Float16)v.z, (_Float16)v.w};
  *(uint64_t*)(dst + (size_t)i * 4) = *(const uint64_t*)o;
}

template <int K>
__device__ inline void stage_w(const _Float16* __restrict__ src,
                               _Float16* __restrict__ wlds, int tid) {
  constexpr int C = 64 * K / 8;
#pragma unroll 4
  for (int ci = tid; ci < C; ci += NTHREADS) {
    const int r = ci / (K / 8);
    const int kc = (ci % (K / 8)) * 8;
    *(f16x8*)(wlds + (size_t)r * KPAD + kc) = *(const f16x8*)(src + (size_t)r * K + kc);
  }
}

// ---- wave's GEMM share: ONE B-slice feeds TWO A row-tiles (gt=gp*2, gp*2+1).
// mfma 16x16x32_f16 (H1, HW-verified): A m=lane&15, k=(lane>>4)*8+j ;
// B n=lane&15 same k ; D col=lane&15, row=(lane>>4)*4+reg.
template <int NS>
__device__ inline void do_gemm2(const _Float16* __restrict__ bbase,
                                const _Float16* __restrict__ wlds,
                                int aKoff, int bKoff, int lane, int gp, int nt,
                                f32x4& acc0, f32x4& acc1) {
  const int bcol = nt * 16 + (lane & 15);
  const int krow = (lane >> 4) * 8;
  const _Float16* arow0 = wlds + (size_t)(gp * 32 + (lane & 15)) * KPAD + aKoff + krow;
  const _Float16* arow1 = arow0 + (size_t)16 * KPAD;
  const _Float16* brow  = bbase + (size_t)bcol * HD + bKoff + krow;
  constexpr int CH = (NS > 8) ? 8 : NS;
#pragma unroll
  for (int base = 0; base < NS; base += CH) {
    f16x8 br[CH];
#pragma unroll
    for (int s = 0; s < CH; ++s) br[s] = *(const f16x8*)(brow + (base + s) * 32);
#pragma unroll
    for (int s = 0; s < CH; ++s) {
      f16x8 a0 = *(const f16x8*)(arow0 + (base + s) * 32);
      acc0 = __builtin_amdgcn_mfma_f32_16x16x32_f16(a0, br[s], acc0, 0, 0, 0);
      f16x8 a1 = *(const f16x8*)(arow1 + (base + s) * 32);
      acc1 = __builtin_amdgcn_mfma_f32_16x16x32_f16(a1, br[s], acc1, 0, 0, 0);
    }
  }
}

// ---- per-group flag barrier (verified ≡ grid.sync, rounds 2/3) -------------
__device__ inline void group_barrier(unsigned* slots, int cg, unsigned target,
                                     int lane, int wave, bool& dead) {
  __syncthreads();
  if (wave == 0) {
    if (lane == 0) {
      __builtin_amdgcn_fence(__ATOMIC_RELEASE, "agent");
      __hip_atomic_store(&slots[cg], target, __ATOMIC_RELAXED, __HIP_MEMORY_SCOPE_AGENT);
    }
    if (!dead) {
      unsigned* myslot = &slots[lane & 31];
      int spins = 0;
      while (true) {
        unsigned v = __hip_atomic_load(myslot, __ATOMIC_RELAXED, __HIP_MEMORY_SCOPE_AGENT);
        if (__all((int)(v >= target))) break;
        __builtin_amdgcn_s_sleep(1);
        if (++spins > (1 << 22)) { dead = true; break; }
      }
    }
    if (lane == 0) __builtin_amdgcn_fence(__ATOMIC_ACQUIRE, "agent");
  }
  __syncthreads();
}

__global__ __launch_bounds__(NTHREADS, 2) void lstm3_kernel(
    const float* __restrict__ x,
    const float* __restrict__ wih0,
    const float* __restrict__ bih0, const float* __restrict__ bhh0,
    const float* __restrict__ bih1, const float* __restrict__ bhh1,
    const float* __restrict__ bih2, const float* __restrict__ bhh2,
    const float* __restrict__ wfc, const float* __restrict__ bfc,
    float* __restrict__ out, char* __restrict__ ws) {
  __shared__ __align__(16) char smem[149504];
  _Float16* wlds = (_Float16*)smem;                 // [64][KPAD] fp16
  float* biasLds = (float*)(smem + 132096);         // [64]
  float* w0Lds   = (float*)(smem + 132352);         // [64]
  float* gmat    = (float*)(smem + 132608);         // [128][33] f32 (kh-major)

  const int bid = blockIdx.x;
  const int grp = bid & 7;
  const int cg  = bid >> 3;
  const int tid = threadIdx.x;
  const int lane = tid & 63;
  const int wave = tid >> 6;
  const int gp = wave & 1;        // gate pair: 0 -> i,f ; 1 -> g,o
  const int nt = (wave >> 1) & 1; // batch half 0/1
  const int kh = wave >> 2;       // K half 0/1
  const int nbase = cg * 16;
  const int ab = tid >> 4;        // epilogue cell: local batch 0..31
  const int an = tid & 15;        // epilogue cell: local col 0..15

  unsigned* bar = (unsigned*)ws + grp * 64;
  const _Float16* wcv0 = (const _Float16*)(ws + W0_OFF) + (size_t)cg * 64 * 512;
  const _Float16* wcv1 = (const _Float16*)(ws + W1_OFF) + (size_t)cg * 64 * 1024;
  const _Float16* wcv2 = (const _Float16*)(ws + W2_OFF) + (size_t)cg * 64 * 1024;
  _Float16* h2b  = (_Float16*)(ws + H2_OFF);
  _Float16* ring = (_Float16*)(ws + RING_OFF);
  _Float16* seq0 = (_Float16*)(ws + SEQ0_OFF);

  unsigned barIdx = 0;
  bool dead = false;

  auto seqTile  = [&](int t) { return seq0 + ((size_t)(grp * SEQ + t)) * TILE_H; };
  auto ringTile = [&](int t) { return ring + ((size_t)(t % RSLOTS) * NGRP + grp) * TILE_H; };
  auto h2Tile   = [&](int s) { return h2b + ((size_t)s * NGRP + grp) * TILE_H; };

  // step with optional L2-warming prefetch (pf1: tid<128, pf2: tid in [128,256);
  // 2KB each; results sunk via asm before the barrier so loads stay live).
  auto step = [&](const _Float16* recB, const _Float16* inB, float xv, float& cst,
                  _Float16* houtTile, bool skip,
                  const char* pf1, const char* pf2) {
    float pfacc = 0.f;
    if (pf1 != nullptr && tid < 128) {
      float4 v = ((const float4*)pf1)[tid];
      pfacc += v.x + v.y + v.z + v.w;
    }
    if (pf2 != nullptr && tid >= 128 && tid < 256) {
      float4 v = ((const float4*)pf2)[tid - 128];
      pfacc += v.x + v.y + v.z + v.w;
    }
    f32x4 acc0 = {0.f, 0.f, 0.f, 0.f};
    f32x4 acc1 = {0.f, 0.f, 0.f, 0.f};
    if (!skip) {
      if (inB == nullptr) {
        do_gemm2<8>(recB, wlds, kh * 256, kh * 256, lane, gp, nt, acc0, acc1);
      } else {
        const _Float16* bb = kh ? inB : recB;
        do_gemm2<16>(bb, wlds, kh * 512, 0, lane, gp, nt, acc0, acc1);
      }
    }
    {
      const int r0 = (lane >> 4) * 4, cb = lane & 15;
      const int colb = nt * 16 + cb;
      const int rb0 = kh * 64 + gp * 32;   // flat row base (gt = gp*2)
#pragma unroll
      for (int r = 0; r < 4; ++r) {
        gmat[(rb0 + r0 + r) * 33 + colb]      = acc0[r];
        gmat[(rb0 + 16 + r0 + r) * 33 + colb] = acc1[r];
      }
    }
    __syncthreads();
    float pre[4];
#pragma unroll
    for (int g = 0; g < 4; ++g) {
      float s = gmat[(g * 16 + an) * 33 + ab] + gmat[((4 + g) * 16 + an) * 33 + ab];
      pre[g] = s + biasLds[g * 16 + an] + xv * w0Lds[g * 16 + an];
    }
    const float gi = sigm(pre[0]);
    const float gf = sigm(pre[1]);
    const float gg = tanhf_(pre[2]);
    const float go = sigm(pre[3]);
    cst = gf * cst + gi * gg;
    const float h = go * tanhf_(cst);
    houtTile[(size_t)ab * HD + nbase + an] = (_Float16)h;
    asm volatile("" :: "v"(pfacc));   // keep prefetch loads live
    group_barrier(bar, cg, ++barIdx, lane, wave, dead);
  };

  // ---------------- phase A: layer 0 (K=512, input is scalar x) -------------
  stage_w<512>(wcv0, wlds, tid);
  if (tid < 64) {
    const int grow2 = (tid >> 4) * 512 + nbase + (tid & 15);
    biasLds[tid] = bih0[grow2] + bhh0[grow2];
    w0Lds[tid] = wih0[grow2];
  }
  __syncthreads();

  float c0 = 0.f;
  for (int t = 0; t < SEQ; ++t) {
    const _Float16* recB = t ? seqTile(t - 1) : seq0;
    const float xv = x[(size_t)(grp * 32 + ab) * SEQ + t];
    const char* pf1 = nullptr;
    if (t >= 384 && t < 448)  pf1 = (const char*)wcv1 + (size_t)(t - 384) * 2048;
    else if (t >= 448)        pf1 = (const char*)seqTile(t - 448) + (size_t)cg * 2048;
    step(recB, nullptr, xv, c0, seqTile(t), t == 0, pf1, nullptr);
  }
  const float c0sav = c0;
  const _Float16* h0tile = seqTile(SEQ - 1);

  // ---------------- phase B: layers 1+2 interleaved in chunks ---------------
  float c1 = c0sav, c2 = c0sav;
  for (int ch = 0; ch < SEQ / TCHUNK; ++ch) {
    // L1 sub-phase
    __syncthreads();
    stage_w<1024>(wcv1, wlds, tid);
    if (tid < 64) {
      const int grow2 = (tid >> 4) * 512 + nbase + (tid & 15);
      biasLds[tid] = bih1[grow2] + bhh1[grow2];
      w0Lds[tid] = 0.f;
    }
    __syncthreads();
    for (int tt = 0; tt < TCHUNK; ++tt) {
      const int t = ch * TCHUNK + tt;
      const _Float16* recB = t ? ringTile(t - 1) : h0tile;
      const char* pf1 = (const char*)wcv2 + (size_t)tt * 2048;   // this chunk's W2
      step(recB, seqTile(t), 0.f, c1, ringTile(t), false, pf1, nullptr);
    }
    // L2 sub-phase
    __syncthreads();
    stage_w<1024>(wcv2, wlds, tid);
    if (tid < 64) {
      const int grow2 = (tid >> 4) * 512 + nbase + (tid & 15);
      biasLds[tid] = bih2[grow2] + bhh2[grow2];
      w0Lds[tid] = 0.f;
    }
    __syncthreads();
    const bool more = (ch + 1) < SEQ / TCHUNK;
    for (int tt = 0; tt < TCHUNK; ++tt) {
      const int t = ch * TCHUNK + tt;
      const _Float16* recB = t ? h2Tile((t - 1) & 1) : h0tile;
      const char* pf1 = more ? (const char*)seqTile((ch + 1) * TCHUNK + tt) +
                               (size_t)cg * 2048 : nullptr;      // next chunk seq0
      const char* pf2 = more ? (const char*)wcv1 + (size_t)tt * 2048 : nullptr;
      step(recB, ringTile(t), 0.f, c2, h2Tile(t & 1), false, pf1, pf2);
    }
  }

  // ---------------- final FC: out[b,:] = h2[b,:] @ Wfc^T + bfc (FLOAT32) ----
  {
    const _Float16* h2 = h2Tile((SEQ - 1) & 1) + (size_t)cg * HD;  // batch row cg
    if (tid < 384) {
      const int pc = tid >> 2, kq = tid & 3;
      const float* wrow = wfc + (size_t)pc * HD + kq * 128;
      const _Float16* hh = h2 + kq * 128;
      float a = 0.f;
#pragma unroll 8
      for (int k2 = 0; k2 < 128; ++k2) a += (float)hh[k2] * wrow[k2];
      gmat[pc * 4 + kq] = a;
    }
    __syncthreads();
    if (tid < 96) {
      const float a = gmat[tid * 4] + gmat[tid * 4 + 1] + gmat[tid * 4 + 2] +
                      gmat[tid * 4 + 3] + bfc[tid];
      out[(size_t)(grp * 32 + cg) * 96 + tid] = a;
    }
    if (dead && tid == 0)
      out[(size_t)(grp * 32 + cg) * 96] = 3.0e9f;   // spin-cap diagnostic
  }
}

__global__ void ws_info_kernel(float* out, float v) { out[0] = v; }

extern "C" void kernel_launch(void* const* d_in, const int* in_sizes, int n_in,
                              void* d_out, int out_size, void* d_ws, size_t ws_size,
                              hipStream_t stream) {
  const float* x    = (const float*)d_in[0];
  const float* wih0 = (const float*)d_in[1];
  const float* whh0 = (const float*)d_in[2];
  const float* bih0 = (const float*)d_in[3];
  const float* bhh0 = (const float*)d_in[4];
  const float* wih1 = (const float*)d_in[5];
  const float* whh1 = (const float*)d_in[6];
  const float* bih1 = (const float*)d_in[7];
  const float* bhh1 = (const float*)d_in[8];
  const float* wih2 = (const float*)d_in[9];
  const float* whh2 = (const float*)d_in[10];
  const float* bih2 = (const float*)d_in[11];
  const float* bhh2 = (const float*)d_in[12];
  const float* wfc  = (const float*)d_in[13];
  const float* bfc  = (const float*)d_in[14];
  float* out = (float*)d_out;
  char* ws = (char*)d_ws;

  if (ws_size < WS_NEED) {
    hipLaunchKernelGGL(ws_info_kernel, dim3(1), dim3(1), 0, stream, out,
                       (float)(ws_size >> 20) * 1.0e6f);
    return;
  }

  hipMemsetAsync(ws, 0, 4096, stream);   // barrier flags (every replay)

  _Float16* w0d = (_Float16*)(ws + W0_OFF);
  _Float16* w1d = (_Float16*)(ws + W1_OFF);
  _Float16* w2d = (_Float16*)(ws + W2_OFF);
  hipLaunchKernelGGL((convw<512>),  dim3(32 * 64 * 512 / 4 / 256),  dim3(256), 0, stream,
                     whh0, whh0, w0d);   // K=512: wih arg never accessed
  hipLaunchKernelGGL((convw<1024>), dim3(32 * 64 * 1024 / 4 / 256), dim3(256), 0, stream,
                     whh1, wih1, w1d);
  hipLaunchKernelGGL((convw<1024>), dim3(32 * 64 * 1024 / 4 / 256), dim3(256), 0, stream,
                     whh2, wih2, w2d);

  void* args[] = {(void*)&x, (void*)&wih0, (void*)&bih0, (void*)&bhh0,
                  (void*)&bih1, (void*)&bhh1, (void*)&bih2, (void*)&bhh2,
                  (void*)&wfc, (void*)&bfc, (void*)&out, (void*)&ws};
  hipError_t e = hipLaunchCooperativeKernel((const void*)lstm3_kernel,
                                            dim3(NGRP * BPG), dim3(NTHREADS),
                                            args, 0, stream);
  if (e != hipSuccess) {
    hipLaunchKernelGGL(ws_info_kernel, dim3(1), dim3(1), 0, stream, out, 2.0e12f);
  }
}

// Round 13
// 7459.087 us; speedup vs baseline: 52.6108x; 2.1442x over previous
//
#include <hip/hip_runtime.h>
#include <stdint.h>

// ---------------------------------------------------------------------------
// 3-layer LSTM (B=256,S=512,H=512) + FC(96) -> FLOAT32 out. ROUND-13.
// Base: round-12 (PASSED, 15993us). Delta: XCD-local fast-path barrier.
// Theory: per-step cost dominated by agent-scope fences (buffer_wbl2 L2
// writeback x256 blocks x1536 steps). Groups (grp = bid&7) land on a single
// XCD under the observed round-robin dispatch; same-XCD communication needs
// only vmcnt drain (syncthreads) + L1 invalidate (buffer_inv) -- no wbl2.
// Runtime detection via HW_REG_XCC_ID (m09-verified) keeps correctness
// placement-independent: non-local groups use the full agent fences.
// Guard: if all 256 blocks report the same XCC (bogus hwreg read), force
// slow path (256 blocks cannot fit one XCD).
// Sentinels (float out[0]): <5e8 ws-MB*1e6 | 2e12 launch-fail | 3e9 spin-cap.
// ---------------------------------------------------------------------------

#define NGRP 8
#define BPG 32
#define HD 512
#define SEQ 512
#define TCHUNK 64
#define RSLOTS (TCHUNK + 1)
#define TILE_H (BPG * HD)          // halves per group-tile [32][512]
#define KPAD 1032                  // halves; 16B-granule row stride 129 (odd)
#define NTHREADS 512

typedef _Float16 f16x8 __attribute__((ext_vector_type(8)));
typedef float f32x4 __attribute__((ext_vector_type(4)));

constexpr size_t W0_OFF   = (size_t)1 << 16;
constexpr size_t W0_SZ    = (size_t)32 * 64 * 512 * 2;           // 2MB
constexpr size_t W1_OFF   = W0_OFF + W0_SZ;
constexpr size_t W1_SZ    = (size_t)32 * 64 * 1024 * 2;          // 4MB
constexpr size_t W2_OFF   = W1_OFF + W1_SZ;
constexpr size_t H2_OFF   = W2_OFF + W1_SZ;
constexpr size_t H2_SZ    = (size_t)2 * NGRP * TILE_H * 2;       // 512KB
constexpr size_t RING_OFF = H2_OFF + H2_SZ;
constexpr size_t RING_SZ  = (size_t)RSLOTS * NGRP * TILE_H * 2;  // 16.6MB
constexpr size_t SEQ0_OFF = RING_OFF + RING_SZ;
constexpr size_t SEQ0_SZ  = (size_t)NGRP * SEQ * TILE_H * 2;     // 128MB
constexpr size_t WS_NEED  = SEQ0_OFF + SEQ0_SZ;                  // ~155MB

__device__ inline float sigm(float v) { return 1.f / (1.f + __expf(-v)); }
__device__ inline float tanhf_(float v) {
  float av = fabsf(v);
  float e = __expf(-2.f * av);
  float t = (1.f - e) / (1.f + e);
  return copysignf(t, v);
}

// ---- weight pre-conversion (verified bit-exact, round 5) -------------------
template <int K>
__global__ void convw(const float* __restrict__ whh, const float* __restrict__ wih,
                      _Float16* __restrict__ dst) {
  const int i = blockIdx.x * blockDim.x + threadIdx.x;
  constexpr int TOT = 32 * 64 * K / 4;
  if (i >= TOT) return;
  const int kq = i % (K / 4);
  const int rr = i / (K / 4);
  const int cg = rr >> 6, r = rr & 63;
  const int grow = (r >> 4) * 512 + cg * 16 + (r & 15);
  const int k = kq * 4;
  const float* src = (k < 512) ? (whh + (size_t)grow * 512 + k)
                               : (wih + (size_t)grow * 512 + (k - 512));
  float4 v = *(const float4*)src;
  _Float16 o[4] = {(_Float16)v.x, (_Float16)v.y, (_Float16)v.z, (_Float16)v.w};
  *(uint64_t*)(dst + (size_t)i * 4) = *(const uint64_t*)o;
}

template <int K>
__device__ inline void stage_w(const _Float16* __restrict__ src,
                               _Float16* __restrict__ wlds, int tid) {
  constexpr int C = 64 * K / 8;
#pragma unroll 4
  for (int ci = tid; ci < C; ci += NTHREADS) {
    const int r = ci / (K / 8);
    const int kc = (ci % (K / 8)) * 8;
    *(f16x8*)(wlds + (size_t)r * KPAD + kc) = *(const f16x8*)(src + (size_t)r * K + kc);
  }
}

// ---- wave's GEMM share: ONE B-slice feeds TWO A row-tiles ------------------
template <int NS>
__device__ inline void do_gemm2(const _Float16* __restrict__ bbase,
                                const _Float16* __restrict__ wlds,
                                int aKoff, int bKoff, int lane, int gp, int nt,
                                f32x4& acc0, f32x4& acc1) {
  const int bcol = nt * 16 + (lane & 15);
  const int krow = (lane >> 4) * 8;
  const _Float16* arow0 = wlds + (size_t)(gp * 32 + (lane & 15)) * KPAD + aKoff + krow;
  const _Float16* arow1 = arow0 + (size_t)16 * KPAD;
  const _Float16* brow  = bbase + (size_t)bcol * HD + bKoff + krow;
  constexpr int CH = (NS > 8) ? 8 : NS;
#pragma unroll
  for (int base = 0; base < NS; base += CH) {
    f16x8 br[CH];
#pragma unroll
    for (int s = 0; s < CH; ++s) br[s] = *(const f16x8*)(brow + (base + s) * 32);
#pragma unroll
    for (int s = 0; s < CH; ++s) {
      f16x8 a0 = *(const f16x8*)(arow0 + (base + s) * 32);
      acc0 = __builtin_amdgcn_mfma_f32_16x16x32_f16(a0, br[s], acc0, 0, 0, 0);
      f16x8 a1 = *(const f16x8*)(arow1 + (base + s) * 32);
      acc1 = __builtin_amdgcn_mfma_f32_16x16x32_f16(a1, br[s], acc1, 0, 0, 0);
    }
  }
}

// ---- per-group flag barrier; fast path when group is XCD-local -------------
// local: producer stores are in the shared (same-XCD) L2 after the vmcnt
// drain in __syncthreads; readers only need their L1 invalidated.
// non-local: full agent release/acquire (wbl2 + inv) as in rounds 11/12.
__device__ inline void group_barrier(unsigned* slots, int cg, unsigned target,
                                     int lane, int wave, bool local, bool& dead) {
  __syncthreads();
  if (wave == 0) {
    if (lane == 0) {
      if (!local) __builtin_amdgcn_fence(__ATOMIC_RELEASE, "agent");
      __hip_atomic_store(&slots[cg], target, __ATOMIC_RELAXED, __HIP_MEMORY_SCOPE_AGENT);
    }
    if (!dead) {
      unsigned* myslot = &slots[lane & 31];
      int spins = 0;
      while (true) {
        unsigned v = __hip_atomic_load(myslot, __ATOMIC_RELAXED, __HIP_MEMORY_SCOPE_AGENT);
        if (__all((int)(v >= target))) break;
        __builtin_amdgcn_s_sleep(1);
        if (++spins > (1 << 22)) { dead = true; break; }
      }
    }
    if (lane == 0) {
      if (!local) __builtin_amdgcn_fence(__ATOMIC_ACQUIRE, "agent");
      else asm volatile("buffer_inv\ns_waitcnt vmcnt(0)" ::: "memory");
    }
  }
  __syncthreads();
}

__global__ __launch_bounds__(NTHREADS, 2) void lstm3_kernel(
    const float* __restrict__ x,
    const float* __restrict__ wih0,
    const float* __restrict__ bih0, const float* __restrict__ bhh0,
    const float* __restrict__ bih1, const float* __restrict__ bhh1,
    const float* __restrict__ bih2, const float* __restrict__ bhh2,
    const float* __restrict__ wfc, const float* __restrict__ bfc,
    float* __restrict__ out, char* __restrict__ ws) {
  __shared__ __align__(16) char smem[149504];
  _Float16* wlds = (_Float16*)smem;                 // [64][KPAD] fp16
  float* biasLds = (float*)(smem + 132096);         // [64]
  float* w0Lds   = (float*)(smem + 132352);         // [64]
  float* gmat    = (float*)(smem + 132608);         // [128][33] f32 (kh-major)

  const int bid = blockIdx.x;
  const int grp = bid & 7;
  const int cg  = bid >> 3;
  const int tid = threadIdx.x;
  const int lane = tid & 63;
  const int wave = tid >> 6;
  const int gp = wave & 1;        // gate pair: 0 -> i,f ; 1 -> g,o
  const int nt = (wave >> 1) & 1; // batch half 0/1
  const int kh = wave >> 2;       // K half 0/1
  const int nbase = cg * 16;
  const int ab = tid >> 4;        // epilogue cell: local batch 0..31
  const int an = tid & 15;        // epilogue cell: local col 0..15

  unsigned* bar = (unsigned*)ws + grp * 64;
  const _Float16* wcv0 = (const _Float16*)(ws + W0_OFF) + (size_t)cg * 64 * 512;
  const _Float16* wcv1 = (const _Float16*)(ws + W1_OFF) + (size_t)cg * 64 * 1024;
  const _Float16* wcv2 = (const _Float16*)(ws + W2_OFF) + (size_t)cg * 64 * 1024;
  _Float16* h2b  = (_Float16*)(ws + H2_OFF);
  _Float16* ring = (_Float16*)(ws + RING_OFF);
  _Float16* seq0 = (_Float16*)(ws + SEQ0_OFF);

  unsigned barIdx = 0;
  bool dead = false;

  // ---- runtime XCD-locality detection (one-time, full-fence barrier) -------
  int myxcc = 0;
  asm volatile("s_getreg_b32 %0, hwreg(HW_REG_XCC_ID)" : "=s"(myxcc));
  int* xcds = (int*)(ws + 2048);
  if (tid == 0) xcds[bid] = myxcc;
  group_barrier(bar, cg, ++barIdx, lane, wave, false, dead);
  bool local = true, allsame = true;
  for (int j = 0; j < BPG; ++j) local = local && (xcds[grp + 8 * j] == myxcc);
  for (int j = 0; j < NGRP * BPG; ++j) allsame = allsame && (xcds[j] == myxcc);
  if (allsame) local = false;   // 256 blocks can't fit one XCD: bogus read

  auto seqTile  = [&](int t) { return seq0 + ((size_t)(grp * SEQ + t)) * TILE_H; };
  auto ringTile = [&](int t) { return ring + ((size_t)(t % RSLOTS) * NGRP + grp) * TILE_H; };
  auto h2Tile   = [&](int s) { return h2b + ((size_t)s * NGRP + grp) * TILE_H; };

  auto step = [&](const _Float16* recB, const _Float16* inB, float xv, float& cst,
                  _Float16* houtTile, bool skip,
                  const char* pf1, const char* pf2) {
    float pfacc = 0.f;
    if (pf1 != nullptr && tid < 128) {
      float4 v = ((const float4*)pf1)[tid];
      pfacc += v.x + v.y + v.z + v.w;
    }
    if (pf2 != nullptr && tid >= 128 && tid < 256) {
      float4 v = ((const float4*)pf2)[tid - 128];
      pfacc += v.x + v.y + v.z + v.w;
    }
    f32x4 acc0 = {0.f, 0.f, 0.f, 0.f};
    f32x4 acc1 = {0.f, 0.f, 0.f, 0.f};
    if (!skip) {
      if (inB == nullptr) {
        do_gemm2<8>(recB, wlds, kh * 256, kh * 256, lane, gp, nt, acc0, acc1);
      } else {
        const _Float16* bb = kh ? inB : recB;
        do_gemm2<16>(bb, wlds, kh * 512, 0, lane, gp, nt, acc0, acc1);
      }
    }
    {
      const int r0 = (lane >> 4) * 4, cb = lane & 15;
      const int colb = nt * 16 + cb;
      const int rb0 = kh * 64 + gp * 32;
#pragma unroll
      for (int r = 0; r < 4; ++r) {
        gmat[(rb0 + r0 + r) * 33 + colb]      = acc0[r];
        gmat[(rb0 + 16 + r0 + r) * 33 + colb] = acc1[r];
      }
    }
    __syncthreads();
    float pre[4];
#pragma unroll
    for (int g = 0; g < 4; ++g) {
      float s = gmat[(g * 16 + an) * 33 + ab] + gmat[((4 + g) * 16 + an) * 33 + ab];
      pre[g] = s + biasLds[g * 16 + an] + xv * w0Lds[g * 16 + an];
    }
    const float gi = sigm(pre[0]);
    const float gf = sigm(pre[1]);
    const float gg = tanhf_(pre[2]);
    const float go = sigm(pre[3]);
    cst = gf * cst + gi * gg;
    const float h = go * tanhf_(cst);
    houtTile[(size_t)ab * HD + nbase + an] = (_Float16)h;
    asm volatile("" :: "v"(pfacc));   // keep prefetch loads live
    group_barrier(bar, cg, ++barIdx, lane, wave, local, dead);
  };

  // ---------------- phase A: layer 0 (K=512, input is scalar x) -------------
  stage_w<512>(wcv0, wlds, tid);
  if (tid < 64) {
    const int grow2 = (tid >> 4) * 512 + nbase + (tid & 15);
    biasLds[tid] = bih0[grow2] + bhh0[grow2];
    w0Lds[tid] = wih0[grow2];
  }
  __syncthreads();

  float c0 = 0.f;
  for (int t = 0; t < SEQ; ++t) {
    const _Float16* recB = t ? seqTile(t - 1) : seq0;
    const float xv = x[(size_t)(grp * 32 + ab) * SEQ + t];
    const char* pf1 = nullptr;
    if (t >= 384 && t < 448)  pf1 = (const char*)wcv1 + (size_t)(t - 384) * 2048;
    else if (t >= 448)        pf1 = (const char*)seqTile(t - 448) + (size_t)cg * 2048;
    step(recB, nullptr, xv, c0, seqTile(t), t == 0, pf1, nullptr);
  }
  const float c0sav = c0;
  const _Float16* h0tile = seqTile(SEQ - 1);

  // ---------------- phase B: layers 1+2 interleaved in chunks ---------------
  float c1 = c0sav, c2 = c0sav;
  for (int ch = 0; ch < SEQ / TCHUNK; ++ch) {
    // L1 sub-phase
    __syncthreads();
    stage_w<1024>(wcv1, wlds, tid);
    if (tid < 64) {
      const int grow2 = (tid >> 4) * 512 + nbase + (tid & 15);
      biasLds[tid] = bih1[grow2] + bhh1[grow2];
      w0Lds[tid] = 0.f;
    }
    __syncthreads();
    for (int tt = 0; tt < TCHUNK; ++tt) {
      const int t = ch * TCHUNK + tt;
      const _Float16* recB = t ? ringTile(t - 1) : h0tile;
      const char* pf1 = (const char*)wcv2 + (size_t)tt * 2048;   // this chunk's W2
      step(recB, seqTile(t), 0.f, c1, ringTile(t), false, pf1, nullptr);
    }
    // L2 sub-phase
    __syncthreads();
    stage_w<1024>(wcv2, wlds, tid);
    if (tid < 64) {
      const int grow2 = (tid >> 4) * 512 + nbase + (tid & 15);
      biasLds[tid] = bih2[grow2] + bhh2[grow2];
      w0Lds[tid] = 0.f;
    }
    __syncthreads();
    const bool more = (ch + 1) < SEQ / TCHUNK;
    for (int tt = 0; tt < TCHUNK; ++tt) {
      const int t = ch * TCHUNK + tt;
      const _Float16* recB = t ? h2Tile((t - 1) & 1) : h0tile;
      const char* pf1 = more ? (const char*)seqTile((ch + 1) * TCHUNK + tt) +
                               (size_t)cg * 2048 : nullptr;      // next chunk seq0
      const char* pf2 = more ? (const char*)wcv1 + (size_t)tt * 2048 : nullptr;
      step(recB, ringTile(t), 0.f, c2, h2Tile(t & 1), false, pf1, pf2);
    }
  }

  // ---------------- final FC: out[b,:] = h2[b,:] @ Wfc^T + bfc (FLOAT32) ----
  {
    const _Float16* h2 = h2Tile((SEQ - 1) & 1) + (size_t)cg * HD;  // batch row cg
    if (tid < 384) {
      const int pc = tid >> 2, kq = tid & 3;
      const float* wrow = wfc + (size_t)pc * HD + kq * 128;
      const _Float16* hh = h2 + kq * 128;
      float a = 0.f;
#pragma unroll 8
      for (int k2 = 0; k2 < 128; ++k2) a += (float)hh[k2] * wrow[k2];
      gmat[pc * 4 + kq] = a;
    }
    __syncthreads();
    if (tid < 96) {
      const float a = gmat[tid * 4] + gmat[tid * 4 + 1] + gmat[tid * 4 + 2] +
                      gmat[tid * 4 + 3] + bfc[tid];
      out[(size_t)(grp * 32 + cg) * 96 + tid] = a;
    }
    if (dead && tid == 0)
      out[(size_t)(grp * 32 + cg) * 96] = 3.0e9f;   // spin-cap diagnostic
  }
}

__global__ void ws_info_kernel(float* out, float v) { out[0] = v; }

extern "C" void kernel_launch(void* const* d_in, const int* in_sizes, int n_in,
                              void* d_out, int out_size, void* d_ws, size_t ws_size,
                              hipStream_t stream) {
  const float* x    = (const float*)d_in[0];
  const float* wih0 = (const float*)d_in[1];
  const float* whh0 = (const float*)d_in[2];
  const float* bih0 = (const float*)d_in[3];
  const float* bhh0 = (const float*)d_in[4];
  const float* wih1 = (const float*)d_in[5];
  const float* whh1 = (const float*)d_in[6];
  const float* bih1 = (const float*)d_in[7];
  const float* bhh1 = (const float*)d_in[8];
  const float* wih2 = (const float*)d_in[9];
  const float* whh2 = (const float*)d_in[10];
  const float* bih2 = (const float*)d_in[11];
  const float* bhh2 = (const float*)d_in[12];
  const float* wfc  = (const float*)d_in[13];
  const float* bfc  = (const float*)d_in[14];
  float* out = (float*)d_out;
  char* ws = (char*)d_ws;

  if (ws_size < WS_NEED) {
    hipLaunchKernelGGL(ws_info_kernel, dim3(1), dim3(1), 0, stream, out,
                       (float)(ws_size >> 20) * 1.0e6f);
    return;
  }

  hipMemsetAsync(ws, 0, 8192, stream);   // barrier flags + xcd table

  _Float16* w0d = (_Float16*)(ws + W0_OFF);
  _Float16* w1d = (_Float16*)(ws + W1_OFF);
  _Float16* w2d = (_Float16*)(ws + W2_OFF);
  hipLaunchKernelGGL((convw<512>),  dim3(32 * 64 * 512 / 4 / 256),  dim3(256), 0, stream,
                     whh0, whh0, w0d);   // K=512: wih arg never accessed
  hipLaunchKernelGGL((convw<1024>), dim3(32 * 64 * 1024 / 4 / 256), dim3(256), 0, stream,
                     whh1, wih1, w1d);
  hipLaunchKernelGGL((convw<1024>), dim3(32 * 64 * 1024 / 4 / 256), dim3(256), 0, stream,
                     whh2, wih2, w2d);

  void* args[] = {(void*)&x, (void*)&wih0, (void*)&bih0, (void*)&bhh0,
                  (void*)&bih1, (void*)&bhh1, (void*)&bih2, (void*)&bhh2,
                  (void*)&wfc, (void*)&bfc, (void*)&out, (void*)&ws};
  hipError_t e = hipLaunchCooperativeKernel((const void*)lstm3_kernel,
                                            dim3(NGRP * BPG), dim3(NTHREADS),
                                            args, 0, stream);
  if (e != hipSuccess) {
    hipLaunchKernelGGL(ws_info_kernel, dim3(1), dim3(1), 0, stream, out, 2.0e12f);
  }
}